// Round 14
// baseline (637.249 us; speedup 1.0000x reference)
//
#include <hip/hip_runtime.h>
#include <stdint.h>

#define Hdim 1024
#define Bdim 8
#define Sdim 2048
#define Edim 8
#define Mtot 16384
#define Ntot 8192   // n' = d*8 + e

typedef short bf16x8 __attribute__((ext_vector_type(8)));
typedef unsigned short u16x8 __attribute__((ext_vector_type(8)));
typedef float f32x4 __attribute__((ext_vector_type(4)));

__device__ __forceinline__ unsigned short f2bf(float f) {
  union { float f; unsigned u; } v; v.f = f;
  unsigned r = (v.u + 0x7FFFu + ((v.u >> 16) & 1u)) >> 16;
  return (unsigned short)r;
}

__device__ __forceinline__ void gload16(const void* g, void* l) {
  __builtin_amdgcn_global_load_lds((const __attribute__((address_space(1))) void*)g,
                                   (__attribute__((address_space(3))) void*)l,
                                   16, 0, 0);
}

// ---------------- kernel 1: fused {convert+mean-partials} / {W transpose} ----------
__global__ void k_prep(const float* __restrict__ x,
                       unsigned short* __restrict__ xb,
                       float* __restrict__ part,
                       const float* __restrict__ We,
                       unsigned short* __restrict__ wt) {
  __shared__ float tl[64][65];
  const int bid = blockIdx.x;
  const int t = threadIdx.x;
  if (bid < 512) {
    const int b = bid >> 6;
    const int s0 = (bid & 63) * 32;
    const int hg = (t & 127) << 3;
    const int sp = t >> 7;
    float accv[8];
#pragma unroll
    for (int q = 0; q < 8; ++q) accv[q] = 0.f;
#pragma unroll 4
    for (int i = 0; i < 16; ++i) {
      const int s = s0 + sp + (i << 1);
      const size_t base = ((size_t)b * Sdim + s) * Hdim + hg;
      const float4 lo = *(const float4*)(x + base);
      const float4 hi = *(const float4*)(x + base + 4);
      accv[0] += lo.x; accv[1] += lo.y; accv[2] += lo.z; accv[3] += lo.w;
      accv[4] += hi.x; accv[5] += hi.y; accv[6] += hi.z; accv[7] += hi.w;
      u16x8 pk;
      pk[0] = f2bf(lo.x); pk[1] = f2bf(lo.y); pk[2] = f2bf(lo.z); pk[3] = f2bf(lo.w);
      pk[4] = f2bf(hi.x); pk[5] = f2bf(hi.y); pk[6] = f2bf(hi.z); pk[7] = f2bf(hi.w);
      *(u16x8*)(xb + base) = pk;
    }
    float* pp = part + ((size_t)b * 128 + (bid & 63) * 2 + sp) * Hdim + hg;
#pragma unroll
    for (int q = 0; q < 8; ++q) pp[q] = accv[q];
  } else {
    const int tb = bid - 512;
    const int e = tb >> 8, hb = (tb >> 4) & 15, db = tb & 15;
    const float* src = We + ((size_t)e * Hdim + hb * 64) * Hdim + db * 64;
#pragma unroll
    for (int it = 0; it < 4; ++it) {
      int idx = it * 256 + t;
      int r = idx >> 4, c4 = (idx & 15) << 2;
      const float4 v = *(const float4*)(src + (size_t)r * Hdim + c4);
      tl[r][c4] = v.x; tl[r][c4 + 1] = v.y; tl[r][c4 + 2] = v.z; tl[r][c4 + 3] = v.w;
    }
    __syncthreads();
#pragma unroll
    for (int it = 0; it < 2; ++it) {
      int idx = it * 256 + t;
      int rr = idx >> 3, cg = (idx & 7) << 3;
      u16x8 pk;
#pragma unroll
      for (int q = 0; q < 8; ++q) pk[q] = f2bf(tl[cg + q][rr]);
      const int np = (db * 64 + rr) * 8 + e;
      *(u16x8*)(wt + (size_t)np * Hdim + hb * 64 + cg) = pk;
    }
  }
}

// ---------------- kernel 2: finish mean -> xm [B][H] ------------------------------
__global__ void k_mean(const float* __restrict__ part, float* __restrict__ xm) {
  __shared__ float red[4][64];
  const int b = blockIdx.y, hc = blockIdx.x, t = threadIdx.x;
  const int h = hc * 64 + (t & 63), q = t >> 6;
  float s = 0.f;
  const float* p = part + ((size_t)b * 128 + q * 32) * Hdim + h;
#pragma unroll 8
  for (int c = 0; c < 32; ++c) s += p[(size_t)c * Hdim];
  red[q][t & 63] = s;
  __syncthreads();
  if (t < 64) {
    float v = (red[0][t] + red[1][t]) + (red[2][t] + red[3][t]);
    xm[b * Hdim + hc * 64 + t] = v * (1.0f / 2048.0f);
  }
}

// ---------------- kernel 3: h = relu(xm @ Wr1 + br1) ------------------------------
__global__ void k_r1(const float* __restrict__ xm,
                     const float* __restrict__ Wr1,
                     const float* __restrict__ br1,
                     float* __restrict__ hbuf) {
  __shared__ float xs[Hdim];
  __shared__ float hred[2][128];
  const int b = blockIdx.y, jc = blockIdx.x, t = threadIdx.x;
  for (int k = t; k < Hdim; k += 256) xs[k] = xm[b * Hdim + k];
  __syncthreads();
  const int j = jc * 128 + (t & 127);
  const int kh = (t >> 7) * 512;
  float acc = 0.f;
#pragma unroll 8
  for (int k = 0; k < 512; ++k)
    acc = fmaf(xs[kh + k], Wr1[(size_t)(kh + k) * Hdim + j], acc);
  hred[t >> 7][t & 127] = acc;
  __syncthreads();
  if (t < 128)
    hbuf[b * Hdim + jc * 128 + t] =
        fmaxf(hred[0][t] + hred[1][t] + br1[jc * 128 + t], 0.f);
}

// ---------------- kernel 4: logits + softmax -> routing [B][E] ---------------------
__global__ void k_router2(const float* __restrict__ hbuf,
                          const float* __restrict__ Wr2,
                          const float* __restrict__ br2,
                          float* __restrict__ routing) {
  const int t = threadIdx.x;
  const int e = t & 7;
  const int b = t >> 3;
  float acc = br2[e];
  const float* hb = hbuf + b * Hdim;
#pragma unroll 8
  for (int k = 0; k < Hdim; ++k) acc = fmaf(hb[k], Wr2[k * Edim + e], acc);
  float m = acc;
  for (int d = 1; d < 8; d <<= 1) m = fmaxf(m, __shfl_xor(m, d, 64));
  float p = __expf(acc - m);
  float s = p;
  for (int d = 1; d < 8; d <<= 1) s += __shfl_xor(s, d, 64);
  routing[t] = p / s;
}

// ---------------- kernel 5: 128x128 GEMM, A via LDS, B direct global->VGPR ---------
// 4 waves (2x2, 64x64 each), BK=64. A staged in 16KB LDS (XOR-swizzled, gload16);
// B fragments loaded straight from global (wt is L3/L2-resident; each 128B row
// line is fully consumed per K-step -> zero overfetch). Halves LDS traffic vs
// R13 (96->48 KB/block-iter) at the cost of +32 VGPR (-> 3 blocks/CU).
// B loads issue before the 2nd barrier; its compiler-emitted vmcnt(0) drains
// them alongside the A-stage at no extra cost.
__global__ __launch_bounds__(256, 3)
void k_moe_gemm(const unsigned short* __restrict__ xb,
                const unsigned short* __restrict__ wt,
                const float* __restrict__ be,
                const float* __restrict__ routing,
                float* __restrict__ out) {
  __shared__ char smem[16384];   // As [128][64] bf16; epilogue reuse [128][17] f32
  const int t = threadIdx.x;
  const int wave = t >> 6, lane = t & 63;
  const int la15 = lane & 15;
  const int wr = wave >> 1, wc = wave & 1;

  // L2-banded bijective mapping: xcd = bid&7 owns 16 m-tiles (= batch xcd)
  const int bid = blockIdx.x;
  const int xcd = bid & 7;
  const int i = bid >> 3;             // 0..1023
  const int m0 = (xcd * 16 + (i & 15)) * 128;
  const int n0 = (i >> 4) * 128;

  // A staging: thread covers row (chunk*8 + lane>>3), phys 16B-chunk lane&7,
  // global logical chunk = (lane&7) ^ (lane>>3)  (pre-swizzled source)
  const int cx = (((lane & 7) ^ (lane >> 3)) << 3);
  const unsigned short* aStage = xb + (size_t)(m0 + (lane >> 3)) * Hdim + cx;

  // A fragment reads: row&7 == lane&7; phys chunk = logical ^ (row&7)
  const int aOff = (wr * 64 + la15) * 128;
  const int swz0 = (((lane >> 4) ^ (lane & 7)) << 4);
  const int swz1 = (((4 + (lane >> 4)) ^ (lane & 7)) << 4);

  // B fragment source (global): row = n0 + wc*64 + jj*16 + la15,
  // k = k0 + pass*32 + (lane>>4)*8
  const unsigned short* bGlob =
      wt + (size_t)(n0 + wc * 64 + la15) * Hdim + ((lane >> 4) << 3);

  f32x4 acc[4][4];
#pragma unroll
  for (int ii = 0; ii < 4; ++ii)
#pragma unroll
    for (int jj = 0; jj < 4; ++jj) acc[ii][jj] = (f32x4){0.f, 0.f, 0.f, 0.f};

  for (int k0 = 0; k0 < Hdim; k0 += 64) {
    __syncthreads();   // all A reads of previous tile done
#pragma unroll
    for (int p = 0; p < 4; ++p) {
      const int c = p * 4 + wave;
      gload16(aStage + (size_t)c * 8 * Hdim + k0, smem + c * 1024);
    }
    // B fragments for THIS k-step, straight from global (L2/L3)
    bf16x8 bf0[4], bf1[4];
#pragma unroll
    for (int jj = 0; jj < 4; ++jj) {
      const unsigned short* bp = bGlob + (size_t)jj * 16 * Hdim + k0;
      bf0[jj] = *(const bf16x8*)(bp);
      bf1[jj] = *(const bf16x8*)(bp + 32);
    }
    __syncthreads();   // compiler drains vmcnt before barrier -> A in LDS, B in regs
    {
      bf16x8 af[4];
#pragma unroll
      for (int ii = 0; ii < 4; ++ii)
        af[ii] = *(const bf16x8*)(smem + aOff + ii * 2048 + swz0);
#pragma unroll
      for (int ii = 0; ii < 4; ++ii)
#pragma unroll
        for (int jj = 0; jj < 4; ++jj)
          acc[ii][jj] = __builtin_amdgcn_mfma_f32_16x16x32_bf16(af[ii], bf0[jj], acc[ii][jj], 0, 0, 0);
#pragma unroll
      for (int ii = 0; ii < 4; ++ii)
        af[ii] = *(const bf16x8*)(smem + aOff + ii * 2048 + swz1);
#pragma unroll
      for (int ii = 0; ii < 4; ++ii)
#pragma unroll
        for (int jj = 0; jj < 4; ++jj)
          acc[ii][jj] = __builtin_amdgcn_mfma_f32_16x16x32_bf16(af[ii], bf1[jj], acc[ii][jj], 0, 0, 0);
    }
  }
  __syncthreads();   // all LDS reads done -> safe to reuse as out staging

  // ---------------- epilogue: bias + relu + routing weight + e-reduce ----------------
  // C frag: row = i*16 + (lane>>4)*4 + r (+wr*64), col = j*16 + la15 (+wc*64)
  float* outb = (float*)smem;                 // [128][17] padded f32
  const int bidx = m0 >> 11;                  // == xcd
  const float rw = routing[bidx * Edim + (lane & 7)];
  const bool writer = ((lane & 7) == 0);
#pragma unroll
  for (int j = 0; j < 4; ++j) {
    const int dloc = wc * 8 + j * 2 + ((lane >> 3) & 1);
    const float bias = be[(lane & 7) * Hdim + (n0 >> 3) + dloc];
#pragma unroll
    for (int ii = 0; ii < 4; ++ii) {
#pragma unroll
      for (int r = 0; r < 4; ++r) {
        float v = fmaxf(acc[ii][j][r] + bias, 0.f) * rw;
        v += __shfl_xor(v, 1, 64);
        v += __shfl_xor(v, 2, 64);
        v += __shfl_xor(v, 4, 64);
        if (writer) {
          const int row = wr * 64 + ii * 16 + ((lane >> 4) << 2) + r;
          outb[row * 17 + dloc] = v;
        }
      }
    }
  }
  __syncthreads();
  // coalesced store of the block's 128 x 16 f32 out-tile
  const size_t obase = (size_t)m0 * Hdim + (n0 >> 3);
#pragma unroll
  for (int it = 0; it < 2; ++it) {
    const int idx = it * 256 + t;
    const int r = idx >> 2;
    const int c = (idx & 3) << 2;
    float4 vv;
    vv.x = outb[r * 17 + c];
    vv.y = outb[r * 17 + c + 1];
    vv.z = outb[r * 17 + c + 2];
    vv.w = outb[r * 17 + c + 3];
    *(float4*)(out + obase + (size_t)r * Hdim + c) = vv;
  }
}

extern "C" void kernel_launch(void* const* d_in, const int* in_sizes, int n_in,
                              void* d_out, int out_size, void* d_ws, size_t ws_size,
                              hipStream_t stream) {
  const float* x   = (const float*)d_in[0];
  const float* We  = (const float*)d_in[1];
  const float* be  = (const float*)d_in[2];
  const float* Wr1 = (const float*)d_in[3];
  const float* br1 = (const float*)d_in[4];
  const float* Wr2 = (const float*)d_in[5];
  const float* br2 = (const float*)d_in[6];
  float* out = (float*)d_out;

  char* ws = (char*)d_ws;
  unsigned short* xb = (unsigned short*)ws;                  // 33,554,432 B
  unsigned short* wt = (unsigned short*)(ws + 33554432);     // 16,777,216 B
  float* part    = (float*)(ws + 50331648);                  //  4,194,304 B
  float* xm      = (float*)(ws + 54525952);                  //     32,768 B
  float* hbuf    = (float*)(ws + 54558720);                  //     32,768 B
  float* routing = (float*)(ws + 54591488);                  //        256 B

  k_prep<<<dim3(2560), 256, 0, stream>>>(x, xb, part, We, wt);
  k_mean<<<dim3(16, Bdim), 256, 0, stream>>>(part, xm);
  k_r1<<<dim3(8, Bdim), 256, 0, stream>>>(xm, Wr1, br1, hbuf);
  k_router2<<<1, 64, 0, stream>>>(hbuf, Wr2, br2, routing);
  k_moe_gemm<<<dim3(8192), 256, 0, stream>>>(xb, wt, be, routing, out);
}

// Round 15
// 384.915 us; speedup vs baseline: 1.6556x; 1.6556x over previous
//
#include <hip/hip_runtime.h>
#include <stdint.h>

#define Hdim 1024
#define Bdim 8
#define Sdim 2048
#define Edim 8
#define Mtot 16384
#define Ntot 8192   // n' = d*8 + e

typedef short bf16x8 __attribute__((ext_vector_type(8)));
typedef unsigned short u16x8 __attribute__((ext_vector_type(8)));
typedef float f32x4 __attribute__((ext_vector_type(4)));

__device__ __forceinline__ unsigned short f2bf(float f) {
  union { float f; unsigned u; } v; v.f = f;
  unsigned r = (v.u + 0x7FFFu + ((v.u >> 16) & 1u)) >> 16;
  return (unsigned short)r;
}

__device__ __forceinline__ void gload16(const void* g, void* l) {
  __builtin_amdgcn_global_load_lds((const __attribute__((address_space(1))) void*)g,
                                   (__attribute__((address_space(3))) void*)l,
                                   16, 0, 0);
}

// ---------------- kernel 1: fused {convert+mean-partials} / {W transpose} ----------
__global__ void k_prep(const float* __restrict__ x,
                       unsigned short* __restrict__ xb,
                       float* __restrict__ part,
                       const float* __restrict__ We,
                       unsigned short* __restrict__ wt) {
  __shared__ float tl[64][65];
  const int bid = blockIdx.x;
  const int t = threadIdx.x;
  if (bid < 512) {
    const int b = bid >> 6;
    const int s0 = (bid & 63) * 32;
    const int hg = (t & 127) << 3;
    const int sp = t >> 7;
    float accv[8];
#pragma unroll
    for (int q = 0; q < 8; ++q) accv[q] = 0.f;
#pragma unroll 4
    for (int i = 0; i < 16; ++i) {
      const int s = s0 + sp + (i << 1);
      const size_t base = ((size_t)b * Sdim + s) * Hdim + hg;
      const float4 lo = *(const float4*)(x + base);
      const float4 hi = *(const float4*)(x + base + 4);
      accv[0] += lo.x; accv[1] += lo.y; accv[2] += lo.z; accv[3] += lo.w;
      accv[4] += hi.x; accv[5] += hi.y; accv[6] += hi.z; accv[7] += hi.w;
      u16x8 pk;
      pk[0] = f2bf(lo.x); pk[1] = f2bf(lo.y); pk[2] = f2bf(lo.z); pk[3] = f2bf(lo.w);
      pk[4] = f2bf(hi.x); pk[5] = f2bf(hi.y); pk[6] = f2bf(hi.z); pk[7] = f2bf(hi.w);
      *(u16x8*)(xb + base) = pk;
    }
    float* pp = part + ((size_t)b * 128 + (bid & 63) * 2 + sp) * Hdim + hg;
#pragma unroll
    for (int q = 0; q < 8; ++q) pp[q] = accv[q];
  } else {
    const int tb = bid - 512;
    const int e = tb >> 8, hb = (tb >> 4) & 15, db = tb & 15;
    const float* src = We + ((size_t)e * Hdim + hb * 64) * Hdim + db * 64;
#pragma unroll
    for (int it = 0; it < 4; ++it) {
      int idx = it * 256 + t;
      int r = idx >> 4, c4 = (idx & 15) << 2;
      const float4 v = *(const float4*)(src + (size_t)r * Hdim + c4);
      tl[r][c4] = v.x; tl[r][c4 + 1] = v.y; tl[r][c4 + 2] = v.z; tl[r][c4 + 3] = v.w;
    }
    __syncthreads();
#pragma unroll
    for (int it = 0; it < 2; ++it) {
      int idx = it * 256 + t;
      int rr = idx >> 3, cg = (idx & 7) << 3;
      u16x8 pk;
#pragma unroll
      for (int q = 0; q < 8; ++q) pk[q] = f2bf(tl[cg + q][rr]);
      const int np = (db * 64 + rr) * 8 + e;
      *(u16x8*)(wt + (size_t)np * Hdim + hb * 64 + cg) = pk;
    }
  }
}

// ---------------- kernel 2: finish mean -> xm [B][H] ------------------------------
__global__ void k_mean(const float* __restrict__ part, float* __restrict__ xm) {
  __shared__ float red[4][64];
  const int b = blockIdx.y, hc = blockIdx.x, t = threadIdx.x;
  const int h = hc * 64 + (t & 63), q = t >> 6;
  float s = 0.f;
  const float* p = part + ((size_t)b * 128 + q * 32) * Hdim + h;
#pragma unroll 8
  for (int c = 0; c < 32; ++c) s += p[(size_t)c * Hdim];
  red[q][t & 63] = s;
  __syncthreads();
  if (t < 64) {
    float v = (red[0][t] + red[1][t]) + (red[2][t] + red[3][t]);
    xm[b * Hdim + hc * 64 + t] = v * (1.0f / 2048.0f);
  }
}

// ---------------- kernel 3: h = relu(xm @ Wr1 + br1) ------------------------------
__global__ void k_r1(const float* __restrict__ xm,
                     const float* __restrict__ Wr1,
                     const float* __restrict__ br1,
                     float* __restrict__ hbuf) {
  __shared__ float xs[Hdim];
  __shared__ float hred[2][128];
  const int b = blockIdx.y, jc = blockIdx.x, t = threadIdx.x;
  for (int k = t; k < Hdim; k += 256) xs[k] = xm[b * Hdim + k];
  __syncthreads();
  const int j = jc * 128 + (t & 127);
  const int kh = (t >> 7) * 512;
  float acc = 0.f;
#pragma unroll 8
  for (int k = 0; k < 512; ++k)
    acc = fmaf(xs[kh + k], Wr1[(size_t)(kh + k) * Hdim + j], acc);
  hred[t >> 7][t & 127] = acc;
  __syncthreads();
  if (t < 128)
    hbuf[b * Hdim + jc * 128 + t] =
        fmaxf(hred[0][t] + hred[1][t] + br1[jc * 128 + t], 0.f);
}

// ---------------- kernel 4: logits + softmax -> routing [B][E] ---------------------
__global__ void k_router2(const float* __restrict__ hbuf,
                          const float* __restrict__ Wr2,
                          const float* __restrict__ br2,
                          float* __restrict__ routing) {
  const int t = threadIdx.x;
  const int e = t & 7;
  const int b = t >> 3;
  float acc = br2[e];
  const float* hb = hbuf + b * Hdim;
#pragma unroll 8
  for (int k = 0; k < Hdim; ++k) acc = fmaf(hb[k], Wr2[k * Edim + e], acc);
  float m = acc;
  for (int d = 1; d < 8; d <<= 1) m = fmaxf(m, __shfl_xor(m, d, 64));
  float p = __expf(acc - m);
  float s = p;
  for (int d = 1; d < 8; d <<= 1) s += __shfl_xor(s, d, 64);
  routing[t] = p / s;
}

// ---------------- kernel 5: m97-structure 128x128 fused GEMM (session best) --------
// 4 waves (2x2, 64x64 each), BK=64, single-buffer EXACTLY 32KB LDS.
// Plain __syncthreads() loop (compiler-managed waitcnts), 16B global_load_lds,
// XOR-swizzled LDS, cross-block TLP for DS|MFMA overlap. Measured: 340 us,
// MfmaUtil 36.3%, 809 TF. B must stay in LDS (R14: direct-to-VGPR exposes
// per-wave vmcnt latency -> 19% MfmaUtil).
__global__ __launch_bounds__(256, 4)
void k_moe_gemm(const unsigned short* __restrict__ xb,
                const unsigned short* __restrict__ wt,
                const float* __restrict__ be,
                const float* __restrict__ routing,
                float* __restrict__ out) {
  __shared__ char smem[32768];   // As [128][64] @0, Bs [128][64] @16384; epilogue reuse
  const int t = threadIdx.x;
  const int wave = t >> 6, lane = t & 63;
  const int la15 = lane & 15;
  const int wr = wave >> 1, wc = wave & 1;

  // L2-banded bijective mapping: xcd = bid&7 owns 16 m-tiles (= batch xcd)
  const int bid = blockIdx.x;
  const int xcd = bid & 7;
  const int i = bid >> 3;             // 0..1023
  const int m0 = (xcd * 16 + (i & 15)) * 128;
  const int n0 = (i >> 4) * 128;

  // staging: thread covers row (chunk*8 + lane>>3), phys 16B-chunk lane&7,
  // global logical chunk = (lane&7) ^ (lane>>3)  (pre-swizzled source)
  const int cx = (((lane & 7) ^ (lane >> 3)) << 3);
  const unsigned short* aStage = xb + (size_t)(m0 + (lane >> 3)) * Hdim + cx;
  const unsigned short* bStage = wt + (size_t)(n0 + (lane >> 3)) * Hdim + cx;

  // fragment reads: row&7 == lane&7; phys chunk = logical ^ (row&7)
  const int aOff = (wr * 64 + la15) * 128;
  const int bOff = (wc * 64 + la15) * 128;
  const int swz0 = (((lane >> 4) ^ (lane & 7)) << 4);
  const int swz1 = (((4 + (lane >> 4)) ^ (lane & 7)) << 4);

  f32x4 acc[4][4];
#pragma unroll
  for (int ii = 0; ii < 4; ++ii)
#pragma unroll
    for (int jj = 0; jj < 4; ++jj) acc[ii][jj] = (f32x4){0.f, 0.f, 0.f, 0.f};

  for (int k0 = 0; k0 < Hdim; k0 += 64) {
    __syncthreads();   // all reads of previous tile done
#pragma unroll
    for (int p = 0; p < 4; ++p) {
      const int c = p * 4 + wave;
      gload16(aStage + (size_t)c * 8 * Hdim + k0, smem + c * 1024);
    }
#pragma unroll
    for (int p = 0; p < 4; ++p) {
      const int c = p * 4 + wave;
      gload16(bStage + (size_t)c * 8 * Hdim + k0, smem + 16384 + c * 1024);
    }
    __syncthreads();   // compiler drains vmcnt before barrier -> LDS ready
    {
      bf16x8 af[4], bf[4];
#pragma unroll
      for (int ii = 0; ii < 4; ++ii)
        af[ii] = *(const bf16x8*)(smem + aOff + ii * 2048 + swz0);
#pragma unroll
      for (int jj = 0; jj < 4; ++jj)
        bf[jj] = *(const bf16x8*)(smem + 16384 + bOff + jj * 2048 + swz0);
#pragma unroll
      for (int ii = 0; ii < 4; ++ii)
#pragma unroll
        for (int jj = 0; jj < 4; ++jj)
          acc[ii][jj] = __builtin_amdgcn_mfma_f32_16x16x32_bf16(af[ii], bf[jj], acc[ii][jj], 0, 0, 0);
#pragma unroll
      for (int ii = 0; ii < 4; ++ii)
        af[ii] = *(const bf16x8*)(smem + aOff + ii * 2048 + swz1);
#pragma unroll
      for (int jj = 0; jj < 4; ++jj)
        bf[jj] = *(const bf16x8*)(smem + 16384 + bOff + jj * 2048 + swz1);
#pragma unroll
      for (int ii = 0; ii < 4; ++ii)
#pragma unroll
        for (int jj = 0; jj < 4; ++jj)
          acc[ii][jj] = __builtin_amdgcn_mfma_f32_16x16x32_bf16(af[ii], bf[jj], acc[ii][jj], 0, 0, 0);
    }
  }
  __syncthreads();   // all LDS reads done -> safe to reuse as out staging

  // ---------------- epilogue: bias + relu + routing weight + e-reduce ----------------
  // C frag: row = i*16 + (lane>>4)*4 + r (+wr*64), col = j*16 + la15 (+wc*64)
  float* outb = (float*)smem;                 // [128][17] padded f32
  const int bidx = m0 >> 11;                  // == xcd
  const float rw = routing[bidx * Edim + (lane & 7)];
  const bool writer = ((lane & 7) == 0);
#pragma unroll
  for (int j = 0; j < 4; ++j) {
    const int dloc = wc * 8 + j * 2 + ((lane >> 3) & 1);
    const float bias = be[(lane & 7) * Hdim + (n0 >> 3) + dloc];
#pragma unroll
    for (int ii = 0; ii < 4; ++ii) {
#pragma unroll
      for (int r = 0; r < 4; ++r) {
        float v = fmaxf(acc[ii][j][r] + bias, 0.f) * rw;
        v += __shfl_xor(v, 1, 64);
        v += __shfl_xor(v, 2, 64);
        v += __shfl_xor(v, 4, 64);
        if (writer) {
          const int row = wr * 64 + ii * 16 + ((lane >> 4) << 2) + r;
          outb[row * 17 + dloc] = v;
        }
      }
    }
  }
  __syncthreads();
  // coalesced store of the block's 128 x 16 f32 out-tile
  const size_t obase = (size_t)m0 * Hdim + (n0 >> 3);
#pragma unroll
  for (int it = 0; it < 2; ++it) {
    const int idx = it * 256 + t;
    const int r = idx >> 2;
    const int c = (idx & 3) << 2;
    float4 vv;
    vv.x = outb[r * 17 + c];
    vv.y = outb[r * 17 + c + 1];
    vv.z = outb[r * 17 + c + 2];
    vv.w = outb[r * 17 + c + 3];
    *(float4*)(out + obase + (size_t)r * Hdim + c) = vv;
  }
}

extern "C" void kernel_launch(void* const* d_in, const int* in_sizes, int n_in,
                              void* d_out, int out_size, void* d_ws, size_t ws_size,
                              hipStream_t stream) {
  const float* x   = (const float*)d_in[0];
  const float* We  = (const float*)d_in[1];
  const float* be  = (const float*)d_in[2];
  const float* Wr1 = (const float*)d_in[3];
  const float* br1 = (const float*)d_in[4];
  const float* Wr2 = (const float*)d_in[5];
  const float* br2 = (const float*)d_in[6];
  float* out = (float*)d_out;

  char* ws = (char*)d_ws;
  unsigned short* xb = (unsigned short*)ws;                  // 33,554,432 B
  unsigned short* wt = (unsigned short*)(ws + 33554432);     // 16,777,216 B
  float* part    = (float*)(ws + 50331648);                  //  4,194,304 B
  float* xm      = (float*)(ws + 54525952);                  //     32,768 B
  float* hbuf    = (float*)(ws + 54558720);                  //     32,768 B
  float* routing = (float*)(ws + 54591488);                  //        256 B

  k_prep<<<dim3(2560), 256, 0, stream>>>(x, xb, part, We, wt);
  k_mean<<<dim3(16, Bdim), 256, 0, stream>>>(part, xm);
  k_r1<<<dim3(8, Bdim), 256, 0, stream>>>(xm, Wr1, br1, hbuf);
  k_router2<<<1, 64, 0, stream>>>(hbuf, Wr2, br2, routing);
  k_moe_gemm<<<dim3(8192), 256, 0, stream>>>(xb, wt, be, routing, out);
}